// Round 7
// baseline (135.883 us; speedup 1.0000x reference)
//
#include <hip/hip_runtime.h>

constexpr int EMB_DIM   = 300;
constexpr int HIDDEN    = 256;
constexpr int OUT_DIM   = 3;
constexpr int SEQ       = 128;
constexpr int N_ASPECTS = 8;
constexpr int TILE      = 32;    // bucket padding granularity
constexpr int MTILE     = 16;    // samples per MLP block (2 groups x 8)

// ---------------------------------------------------------------------------
// bf16 helpers (RNE)
// ---------------------------------------------------------------------------
__device__ __forceinline__ unsigned int bfbits(float f) {
  unsigned int u = __float_as_uint(f);
  return (u + 0x7fffu + ((u >> 16) & 1u)) >> 16;
}
__device__ __forceinline__ unsigned int pack2(float lo, float hi) {
  return bfbits(lo) | (bfbits(hi) << 16);
}
__device__ __forceinline__ float blo(unsigned int u) { return __uint_as_float(u << 16); }
__device__ __forceinline__ float bhi(unsigned int u) { return __uint_as_float(u & 0xffff0000u); }

// ---------------------------------------------------------------------------
// Prep: block 0 = deterministic counting-sort bucketing; blocks 1..N convert
// the fp32 table into a SPLIT bf16 layout:
//   A-table [V][256] bf16 -> 512 B rows, line-aligned (offset = id<<9)
//   B-table [V][64]  bf16 -> dims 256..299 padded to 128 B  (offset = id<<7)
// Every token then touches exactly 4+1 cache lines (vs ~6.4 for 600B stride).
// ---------------------------------------------------------------------------
__global__ __launch_bounds__(1024) void prep_kernel(
    const float* __restrict__ emb, unsigned short* __restrict__ embA,
    unsigned short* __restrict__ embB, int vocab,
    const int* __restrict__ aspect, int B, int* __restrict__ perm, int nperm) {
  const int t = threadIdx.x;
  const int lane = t & 63, wave = t >> 6;

  if (blockIdx.x != 0) {
    // one row per wave, grid-stride
    const int cw = (blockIdx.x - 1) * 16 + wave;
    const int nw = (gridDim.x - 1) * 16;
    for (int v = cw; v < vocab; v += nw) {
      const float4* __restrict__ src = (const float4*)(emb + (size_t)v * EMB_DIM);
      float4 p = src[lane];                       // elems 4l..4l+3
      uint2 w;
      w.x = pack2(p.x, p.y); w.y = pack2(p.z, p.w);
      ((uint2*)(embA + (size_t)v * 256))[lane] = w;
      if (lane < 11) {
        float4 q = src[64 + lane];                // elems 256+4l..
        uint2 u;
        u.x = pack2(q.x, q.y); u.y = pack2(q.z, q.w);
        ((uint2*)(embB + (size_t)v * 64))[lane] = u;
      }
    }
    return;
  }

  // ---- block 0: bucketing (16 waves) ----
  __shared__ int wcnt[16][N_ASPECTS];
  __shared__ int cur[16][N_ASPECTS];

  for (int i = t; i < nperm; i += 1024) perm[i] = -1;

  int my_a[8];
  int cnt[N_ASPECTS];
#pragma unroll
  for (int q = 0; q < N_ASPECTS; ++q) cnt[q] = 0;
#pragma unroll
  for (int k = 0; k < 8; ++k) {
    int s = t + k * 1024;
    int a = (s < B) ? aspect[s] : -1;
    my_a[k] = a;
#pragma unroll
    for (int q = 0; q < N_ASPECTS; ++q) cnt[q] += (a == q);
  }
#pragma unroll
  for (int q = 0; q < N_ASPECTS; ++q) {
    int c = cnt[q];
    for (int off = 32; off > 0; off >>= 1) c += __shfl_down(c, off);
    if (lane == 0) wcnt[wave][q] = c;
  }
  __syncthreads();
  if (t == 0) {
    int base = 0;
    for (int q = 0; q < N_ASPECTS; ++q) {
      int tot = 0;
      for (int w = 0; w < 16; ++w) { cur[w][q] = base + tot; tot += wcnt[w][q]; }
      base += ((tot + TILE - 1) / TILE) * TILE;
    }
  }
  __syncthreads();

#pragma unroll
  for (int k = 0; k < 8; ++k) {
    int a = my_a[k];
    int s = t + k * 1024;
#pragma unroll
    for (int q = 0; q < N_ASPECTS; ++q) {
      unsigned long long m = __ballot(a == q);
      if (a == q) {
        int rank = __popcll(m & ((1ull << lane) - 1ull));
        int pos = cur[wave][q] + rank;
        perm[pos] = s;
        if (rank == __popcll(m) - 1) cur[wave][q] = pos + 1;
      }
    }
  }
}

// ---------------------------------------------------------------------------
// Pool: one sample per wave; bitonic-sort ids (vocab-sweep convoy keeps the
// hot window cache-resident; sort bugs can only cost locality, never
// correctness). Phase A: uniform 512B row gather, unroll 8 (deep pipeline).
// Phase B: lanes 0..43 cover 4 tokens/iter (lane = 11*tok + sub), reduced
// with two shfl_downs. Byte offsets precomputed in LDS (shifts only).
// ---------------------------------------------------------------------------
__global__ __launch_bounds__(256) void pool_kernel(
    const int* __restrict__ ids, const unsigned short* __restrict__ embA,
    const unsigned short* __restrict__ embB, float* __restrict__ x, int B) {
  const int wave = threadIdx.x >> 6, lane = threadIdx.x & 63;
  const int b = blockIdx.x * 4 + wave;
  if (b >= B) return;

  int r0 = ids[(size_t)b * SEQ + lane];
  int r1 = ids[(size_t)b * SEQ + lane + 64];

#pragma unroll
  for (int k = 2; k <= 128; k <<= 1) {
#pragma unroll
    for (int j = k >> 1; j >= 1; j >>= 1) {
      if (j == 64) {
        int lo = min(r0, r1), hi = max(r0, r1);
        r0 = lo; r1 = hi;
      } else {
        const bool up0 = ((lane & k) == 0);
        const bool up1 = (((lane + 64) & k) == 0);
        const bool side = ((lane & j) == 0);
        int o0 = __shfl_xor(r0, j);
        int o1 = __shfl_xor(r1, j);
        r0 = (side == up0) ? min(r0, o0) : max(r0, o0);
        r1 = (side == up1) ? min(r1, o1) : max(r1, o1);
      }
    }
  }

  __shared__ int sA[4][SEQ];
  __shared__ int sB[4][SEQ];
  sA[wave][lane]      = r0 << 9;   // A byte offset
  sA[wave][lane + 64] = r1 << 9;
  sB[wave][lane]      = r0 << 7;   // B byte offset
  sB[wave][lane + 64] = r1 << 7;
  __syncthreads();

  // phase A: dims 4*lane .. 4*lane+3
  float a0 = 0.f, a1 = 0.f, a2 = 0.f, a3 = 0.f;
  const char* __restrict__ baseA = (const char*)embA + (size_t)lane * 8;
#pragma unroll 8
  for (int s = 0; s < SEQ; ++s) {
    uint2 v = *(const uint2*)(baseA + sA[wave][s]);
    a0 += blo(v.x); a1 += bhi(v.x); a2 += blo(v.y); a3 += bhi(v.y);
  }

  // phase B: lanes 0..43, 4 tokens per iter; dims 256+4*sub .. +3
  const int myTok = lane / 11;             // hoisted magic-mul
  const int mySub = lane - myTok * 11;
  float c0 = 0.f, c1 = 0.f, c2 = 0.f, c3 = 0.f;
  if (lane < 44) {
    const char* __restrict__ baseB = (const char*)embB + (size_t)mySub * 8;
#pragma unroll 8
    for (int s = 0; s < SEQ; s += 4) {
      uint2 v = *(const uint2*)(baseB + sB[wave][s + myTok]);
      c0 += blo(v.x); c1 += bhi(v.x); c2 += blo(v.y); c3 += bhi(v.y);
    }
  }
  // reduce the 4 token-groups (lanes l, l+11, l+22, l+33)
  c0 += __shfl_down(c0, 22); c1 += __shfl_down(c1, 22);
  c2 += __shfl_down(c2, 22); c3 += __shfl_down(c3, 22);
  c0 += __shfl_down(c0, 11); c1 += __shfl_down(c1, 11);
  c2 += __shfl_down(c2, 11); c3 += __shfl_down(c3, 11);

  const float sc = 1.0f / (float)SEQ;
  float4* __restrict__ xr = (float4*)(x + (size_t)b * EMB_DIM);
  xr[lane] = make_float4(a0 * sc, a1 * sc, a2 * sc, a3 * sc);
  if (lane < 11) {
    float4* __restrict__ xb = (float4*)(x + (size_t)b * EMB_DIM + 256);
    xb[lane] = make_float4(c0 * sc, c1 * sc, c2 * sc, c3 * sc);
  }
}

// ---------------------------------------------------------------------------
// Routed MLP, split-K: 4 waves = 2 groups x 2 K-halves. All register-array
// indices compile-time static (rule #20); kw-dependent paths via wave-uniform
// if/else; __syncthreads outside the branches.
// ---------------------------------------------------------------------------
__global__ __launch_bounds__(256) void mlp_kernel(
    const float* __restrict__ x, const int* __restrict__ aspect,
    const int* __restrict__ perm,
    const float* __restrict__ W1, const float* __restrict__ b1,
    const float* __restrict__ W2, const float* __restrict__ b2,
    float* __restrict__ out) {
  const int t = threadIdx.x;
  const int wave = t >> 6, lane = t & 63;
  const int g = wave >> 1;
  const int kw = wave & 1;
  const int start = blockIdx.x * MTILE;

  __shared__ int ss[MTILE];
  __shared__ float xch[2][8][64][4];

  if (t < MTILE) ss[t] = perm[start + t];
  __syncthreads();
  const int s0 = ss[0];
  if (s0 < 0) return;
  const int a = aspect[s0];

  int smp[8];
  const float* xrow[8];
#pragma unroll
  for (int s = 0; s < 8; ++s) {
    int m = __builtin_amdgcn_readfirstlane(ss[g * 8 + s]);
    smp[s] = m;
    xrow[s] = x + (size_t)(m < 0 ? s0 : m) * EMB_DIM;
  }

  const float4* __restrict__ w1r =
      (const float4*)(W1 + (size_t)a * EMB_DIM * HIDDEN) + lane;
  float4 acc[8];
  if (kw == 0) {
    const float4 bb = ((const float4*)(b1 + a * HIDDEN))[lane];
#pragma unroll
    for (int s = 0; s < 8; ++s) acc[s] = bb;
  } else {
#pragma unroll
    for (int s = 0; s < 8; ++s) acc[s] = make_float4(0.f, 0.f, 0.f, 0.f);
  }
  const int d0 = kw ? 160 : 0;
  const int d1 = kw ? EMB_DIM : 160;
  for (int d = d0; d < d1; d += 4) {
    float4 xv[8];
#pragma unroll
    for (int s = 0; s < 8; ++s) xv[s] = *(const float4*)(xrow[s] + d);
#pragma unroll
    for (int dd = 0; dd < 4; ++dd) {
      const float4 w = w1r[(size_t)(d + dd) * (HIDDEN / 4)];
#pragma unroll
      for (int s = 0; s < 8; ++s) {
        const float xs = dd == 0 ? xv[s].x : dd == 1 ? xv[s].y
                        : dd == 2 ? xv[s].z : xv[s].w;
        acc[s].x = fmaf(xs, w.x, acc[s].x);
        acc[s].y = fmaf(xs, w.y, acc[s].y);
        acc[s].z = fmaf(xs, w.z, acc[s].z);
        acc[s].w = fmaf(xs, w.w, acc[s].w);
      }
    }
  }

  if (kw == 0) {
#pragma unroll
    for (int i = 0; i < 4; ++i)
      *(float4*)&xch[g][4 + i][lane][0] = acc[4 + i];
  } else {
#pragma unroll
    for (int i = 0; i < 4; ++i)
      *(float4*)&xch[g][i][lane][0] = acc[i];
  }
  __syncthreads();

  const float4* __restrict__ w2p =
      (const float4*)(W2 + (size_t)a * HIDDEN * OUT_DIM + lane * 12);
  const float4 w2a = w2p[0];
  const float4 w2b = w2p[1];
  const float4 w2c = w2p[2];

  float4 own[4];
  int ms[4];
  if (kw == 0) {
    own[0] = acc[0]; own[1] = acc[1]; own[2] = acc[2]; own[3] = acc[3];
    ms[0] = smp[0]; ms[1] = smp[1]; ms[2] = smp[2]; ms[3] = smp[3];
  } else {
    own[0] = acc[4]; own[1] = acc[5]; own[2] = acc[6]; own[3] = acc[7];
    ms[0] = smp[4]; ms[1] = smp[5]; ms[2] = smp[6]; ms[3] = smp[7];
  }
  const int mys = 4 * kw;

  float p[4][OUT_DIM];
#pragma unroll
  for (int i = 0; i < 4; ++i) {
    const float4 pr = *(const float4*)&xch[g][mys + i][lane][0];
    const float h0 = fmaxf(own[i].x + pr.x, 0.f);
    const float h1 = fmaxf(own[i].y + pr.y, 0.f);
    const float h2 = fmaxf(own[i].z + pr.z, 0.f);
    const float h3 = fmaxf(own[i].w + pr.w, 0.f);
    p[i][0] = fmaf(h0, w2a.x, fmaf(h1, w2a.w, fmaf(h2, w2b.z, h3 * w2c.y)));
    p[i][1] = fmaf(h0, w2a.y, fmaf(h1, w2b.x, fmaf(h2, w2b.w, h3 * w2c.z)));
    p[i][2] = fmaf(h0, w2a.z, fmaf(h1, w2b.y, fmaf(h2, w2c.x, h3 * w2c.w)));
  }
#pragma unroll
  for (int off = 32; off > 0; off >>= 1)
#pragma unroll
    for (int i = 0; i < 4; ++i) {
      p[i][0] += __shfl_down(p[i][0], off);
      p[i][1] += __shfl_down(p[i][1], off);
      p[i][2] += __shfl_down(p[i][2], off);
    }

  if (lane == 0) {
    const float g0 = b2[a * OUT_DIM + 0];
    const float g1 = b2[a * OUT_DIM + 1];
    const float g2 = b2[a * OUT_DIM + 2];
#pragma unroll
    for (int i = 0; i < 4; ++i) {
      if (ms[i] >= 0) {
        float* o = out + (size_t)ms[i] * OUT_DIM;
        o[0] = p[i][0] + g0;
        o[1] = p[i][1] + g1;
        o[2] = p[i][2] + g2;
      }
    }
  }
}

// ---------------------------------------------------------------------------
extern "C" void kernel_launch(void* const* d_in, const int* in_sizes, int n_in,
                              void* d_out, int out_size, void* d_ws, size_t ws_size,
                              hipStream_t stream) {
  const int*   ids    = (const int*)d_in[0];
  const int*   aspect = (const int*)d_in[1];
  const float* emb    = (const float*)d_in[2];
  const float* W1     = (const float*)d_in[3];
  const float* b1     = (const float*)d_in[4];
  const float* W2     = (const float*)d_in[5];
  const float* b2     = (const float*)d_in[6];
  float*       out    = (float*)d_out;

  const int B     = in_sizes[1];
  const int nemb  = in_sizes[2];
  const int VOCAB = nemb / EMB_DIM;            // 50000
  const int nblk  = (B + TILE - 1) / TILE + N_ASPECTS;
  const int nperm = nblk * TILE;

  // workspace: [x: B*300 f32][perm][embA: V*256 bf16 (512B-aligned)][embB: V*64 bf16]
  float* x    = (float*)d_ws;
  int*   perm = (int*)((char*)d_ws + (size_t)B * EMB_DIM * sizeof(float));
  size_t offA = ((size_t)B * EMB_DIM * sizeof(float) + (size_t)nperm * 4 + 511) & ~(size_t)511;
  unsigned short* embA = (unsigned short*)((char*)d_ws + offA);
  unsigned short* embB = embA + (size_t)VOCAB * 256;

  prep_kernel<<<513, 1024, 0, stream>>>(emb, embA, embB, VOCAB,
                                        aspect, B, perm, nperm);
  pool_kernel<<<(B + 3) / 4, 256, 0, stream>>>(ids, embA, embB, x, B);
  mlp_kernel<<<nperm / MTILE, 256, 0, stream>>>(x, aspect, perm, W1, b1, W2, b2, out);
}